// Round 12
// baseline (125.189 us; speedup 1.0000x reference)
//
#include <hip/hip_runtime.h>
#include <hip/hip_fp16.h>

#define D_FEAT 64

// Prep (fused): [0, rb) blocks split-repack feat f32 -> two fp16 arrays
// A=[N][32], B=[N][32] (3.2MB each; each fits a 4MiB per-XCD L2).
// [rb, rb+eb) build row_ptr via edge-parallel boundary scatter.
__global__ __launch_bounds__(256) void prep_kernel(
    const float* __restrict__ feat,
    uint2* __restrict__ fA, uint2* __restrict__ fB,
    const int* __restrict__ edge_dst, int* __restrict__ rp,
    int n_nodes, int n_edges, int rb) {
  if ((int)blockIdx.x < rb) {
    const int i = blockIdx.x * blockDim.x + threadIdx.x;  // float4 index
    const int n_vec4 = n_nodes * 16;
    if (i >= n_vec4) return;
    const int node = i >> 4;
    const int c4   = i & 15;            // which float4 within the 64-f row
    const float4 v = ((const float4*)feat)[i];
    const __half2 h0 = __float22half2_rn(make_float2(v.x, v.y));
    const __half2 h1 = __float22half2_rn(make_float2(v.z, v.w));
    uint2 o;
    o.x = *(const unsigned int*)&h0;
    o.y = *(const unsigned int*)&h1;
    uint2* dst = (c4 < 8) ? fA : fB;
    dst[node * 8 + (c4 & 7)] = o;
  } else {
    const int e = (blockIdx.x - rb) * blockDim.x + threadIdx.x;
    if (e > n_edges) return;
    const int d0 = (e == 0) ? -1 : edge_dst[e - 1];
    const int d1 = (e == n_edges) ? n_nodes : edge_dst[e];
    for (int v = d0 + 1; v <= d1; ++v) rp[v] = e;
  }
}

// Gather over a 32-feature half (fp16 rows of 64B). One wave per dst node.
// lane = 4*slot + part: 16 edge slots x 4 lanes; one dwordx4 per lane = 16B
// -> one edge = one coalesced 64B request. Working set 3.2MB -> L2-resident
// per XCD; two sequential launches cover the two halves.
__global__ __launch_bounds__(256) void gcn_gather_half(
    const uint4* __restrict__ fh,       // [n_nodes*4] 16B chunks
    const float* __restrict__ ew,
    const int* __restrict__ esrc,
    const int* __restrict__ rp,
    float* __restrict__ out, int n_nodes, int col_off) {
  const int wave = (blockIdx.x * blockDim.x + threadIdx.x) >> 6;
  const int lane = threadIdx.x & 63;
  if (wave >= n_nodes) return;
  const int slot = lane >> 2;   // edge slot 0..15
  const int part = lane & 3;    // 16B chunk within the 64B half-row

  const int e0 = rp[wave];
  const int e1 = rp[wave + 1];

  float a0 = 0.f, a1 = 0.f, a2 = 0.f, a3 = 0.f;
  float a4 = 0.f, a5 = 0.f, a6 = 0.f, a7 = 0.f;

  for (int base = e0; base < e1; base += 64) {
    const int n = min(64, e1 - base);
    int   s = 0;
    float w = 0.0f;
    if (lane < n) {
      s = esrc[base + lane];
      w = ew[base + lane];   // padded slots carry w=0 -> contribute zero
    }
#pragma unroll
    for (int r = 0; r < 4; ++r) {       // r*16+slot <= 63
      const int   sk = __shfl(s, r * 16 + slot);
      const float wk = __shfl(w, r * 16 + slot);
      const uint4 q  = fh[(size_t)sk * 4 + part];
      const float2 f0 = __half22float2(*(const __half2*)&q.x);
      const float2 f1 = __half22float2(*(const __half2*)&q.y);
      const float2 f2 = __half22float2(*(const __half2*)&q.z);
      const float2 f3 = __half22float2(*(const __half2*)&q.w);
      a0 = fmaf(f0.x, wk, a0); a1 = fmaf(f0.y, wk, a1);
      a2 = fmaf(f1.x, wk, a2); a3 = fmaf(f1.y, wk, a3);
      a4 = fmaf(f2.x, wk, a4); a5 = fmaf(f2.y, wk, a5);
      a6 = fmaf(f3.x, wk, a6); a7 = fmaf(f3.y, wk, a7);
    }
  }

  // Reduce the 16 slot-partials (lane bits 2..5); part stays fixed.
#pragma unroll
  for (int m = 4; m <= 32; m <<= 1) {
    a0 += __shfl_xor(a0, m); a1 += __shfl_xor(a1, m);
    a2 += __shfl_xor(a2, m); a3 += __shfl_xor(a3, m);
    a4 += __shfl_xor(a4, m); a5 += __shfl_xor(a5, m);
    a6 += __shfl_xor(a6, m); a7 += __shfl_xor(a7, m);
  }

  if (slot == 0) {                      // lanes 0..3, part == lane
    float4* orow = (float4*)(out + (size_t)wave * D_FEAT + col_off);
    orow[part * 2]     = make_float4(a0, a1, a2, a3);
    orow[part * 2 + 1] = make_float4(a4, a5, a6, a7);
  }
}

extern "C" void kernel_launch(void* const* d_in, const int* in_sizes, int n_in,
                              void* d_out, int out_size, void* d_ws, size_t ws_size,
                              hipStream_t stream) {
  const float* feat        = (const float*)d_in[0];
  const float* edge_weight = (const float*)d_in[1];
  const int*   edge_src    = (const int*)d_in[2];
  const int*   edge_dst    = (const int*)d_in[3];
  float* out = (float*)d_out;

  const int n_edges = in_sizes[1];            // E = 1,250,000
  const int n_nodes = out_size / D_FEAT;      // N = 50,000

  int*   rp = (int*)d_ws;                               // (N+1) ints
  uint2* fA = (uint2*)((char*)d_ws + (1 << 20));        // 3.2MB half A
  uint2* fB = (uint2*)((char*)d_ws + (1 << 20) + ((size_t)n_nodes * 64));

  const int n_vec4 = n_nodes * 16;
  const int rb = (n_vec4 + 255) / 256;
  const int eb = (n_edges + 1 + 255) / 256;
  prep_kernel<<<rb + eb, 256, 0, stream>>>(
      feat, fA, fB, edge_dst, rp, n_nodes, n_edges, rb);

  const int gblocks = (int)(((long)n_nodes * 64 + 255) / 256);
  gcn_gather_half<<<gblocks, 256, 0, stream>>>(
      (const uint4*)fA, edge_weight, edge_src, rp, out, n_nodes, 0);
  gcn_gather_half<<<gblocks, 256, 0, stream>>>(
      (const uint4*)fB, edge_weight, edge_src, rp, out, n_nodes, 32);
}

// Round 14
// 103.978 us; speedup vs baseline: 1.2040x; 1.2040x over previous
//
#include <hip/hip_runtime.h>
#include <hip/hip_fp16.h>

#define D_FEAT 64

// Fused prep: [0, rb) blocks repack feat f32->f16 (halves gather line
// fills; feat ~N(0,1), fp16 rel err 2^-11 -> absmax 0.0625 << 0.3675).
// [rb, rb+eb) blocks build row_ptr via edge-parallel boundary scatter
// (edge_dst is sorted): rp[v] = first edge with dst >= v.
__global__ __launch_bounds__(256) void prep_kernel(
    const float* __restrict__ feat, uint2* __restrict__ f16,
    const int* __restrict__ edge_dst, int* __restrict__ rp,
    int n_vec4, int n_edges, int n_nodes, int rb) {
  if ((int)blockIdx.x < rb) {
    const int i = blockIdx.x * blockDim.x + threadIdx.x;
    if (i >= n_vec4) return;
    const float4 v = ((const float4*)feat)[i];
    const __half2 h0 = __float22half2_rn(make_float2(v.x, v.y));
    const __half2 h1 = __float22half2_rn(make_float2(v.z, v.w));
    uint2 o;
    o.x = *(const unsigned int*)&h0;
    o.y = *(const unsigned int*)&h1;
    f16[i] = o;
  } else {
    const int e = (blockIdx.x - rb) * blockDim.x + threadIdx.x;
    if (e > n_edges) return;
    const int d0 = (e == 0) ? -1 : edge_dst[e - 1];
    const int d1 = (e == n_edges) ? n_nodes : edge_dst[e];
    for (int v = d0 + 1; v <= d1; ++v) rp[v] = e;
  }
}

// Gather (R10 layout, best measured): one wave per destination node,
// fp16 feat rows (128B). lane = 8*slot + part: 8 edge slots x 8 lanes;
// one dwordx4 per lane = 16B of its slot's row -> one edge = one
// coalesced 128B line request (the per-XCD compulsory-fill floor).
// Fixed 8-round inner loop (w=0 padding) -> unrolled, 8 loads in flight.
__global__ __launch_bounds__(256) void gcn_gather_f16(
    const uint4* __restrict__ feat16,   // [n_nodes*8] 16B chunks
    const float* __restrict__ ew,
    const int* __restrict__ esrc,
    const int* __restrict__ rp,
    float* __restrict__ out, int n_nodes) {
  const int wave = (blockIdx.x * blockDim.x + threadIdx.x) >> 6;
  const int lane = threadIdx.x & 63;
  if (wave >= n_nodes) return;
  const int slot = lane >> 3;   // edge slot 0..7
  const int part = lane & 7;    // 16B chunk within the 128B row

  const int e0 = rp[wave];
  const int e1 = rp[wave + 1];

  float a0 = 0.f, a1 = 0.f, a2 = 0.f, a3 = 0.f;
  float a4 = 0.f, a5 = 0.f, a6 = 0.f, a7 = 0.f;

  for (int base = e0; base < e1; base += 64) {
    const int n = min(64, e1 - base);
    int   s = 0;
    float w = 0.0f;
    if (lane < n) {
      s = esrc[base + lane];
      w = ew[base + lane];   // padded slots carry w=0 -> contribute zero
    }
#pragma unroll
    for (int r = 0; r < 8; ++r) {
      const int   sk = __shfl(s, r * 8 + slot);
      const float wk = __shfl(w, r * 8 + slot);
      const uint4 q  = feat16[(size_t)sk * 8 + part];
      const float2 f0 = __half22float2(*(const __half2*)&q.x);
      const float2 f1 = __half22float2(*(const __half2*)&q.y);
      const float2 f2 = __half22float2(*(const __half2*)&q.z);
      const float2 f3 = __half22float2(*(const __half2*)&q.w);
      a0 = fmaf(f0.x, wk, a0); a1 = fmaf(f0.y, wk, a1);
      a2 = fmaf(f1.x, wk, a2); a3 = fmaf(f1.y, wk, a3);
      a4 = fmaf(f2.x, wk, a4); a5 = fmaf(f2.y, wk, a5);
      a6 = fmaf(f3.x, wk, a6); a7 = fmaf(f3.y, wk, a7);
    }
  }

  // Reduce the 8 slot-partials (lane bits 3,4,5); part stays fixed.
#pragma unroll
  for (int m = 8; m <= 32; m <<= 1) {
    a0 += __shfl_xor(a0, m); a1 += __shfl_xor(a1, m);
    a2 += __shfl_xor(a2, m); a3 += __shfl_xor(a3, m);
    a4 += __shfl_xor(a4, m); a5 += __shfl_xor(a5, m);
    a6 += __shfl_xor(a6, m); a7 += __shfl_xor(a7, m);
  }

  if (slot == 0) {
    float4* orow = (float4*)(out + (size_t)wave * D_FEAT);
    orow[part * 2]     = make_float4(a0, a1, a2, a3);
    orow[part * 2 + 1] = make_float4(a4, a5, a6, a7);
  }
}

extern "C" void kernel_launch(void* const* d_in, const int* in_sizes, int n_in,
                              void* d_out, int out_size, void* d_ws, size_t ws_size,
                              hipStream_t stream) {
  const float* feat        = (const float*)d_in[0];
  const float* edge_weight = (const float*)d_in[1];
  const int*   edge_src    = (const int*)d_in[2];
  const int*   edge_dst    = (const int*)d_in[3];
  float* out = (float*)d_out;

  const int n_edges = in_sizes[1];            // E = 1,250,000
  const int n_nodes = out_size / D_FEAT;      // N = 50,000

  int*   rp  = (int*)d_ws;                             // (N+1) ints
  uint2* f16 = (uint2*)((char*)d_ws + (1 << 20));      // 6.4MB fp16 feat

  const int n_vec4 = n_nodes * (D_FEAT / 4);  // 800K float4s
  const int rb = (n_vec4 + 255) / 256;
  const int eb = (n_edges + 1 + 255) / 256;
  prep_kernel<<<rb + eb, 256, 0, stream>>>(
      feat, f16, edge_dst, rp, n_vec4, n_edges, n_nodes, rb);

  const long total_threads = (long)n_nodes * 64;
  gcn_gather_f16<<<(int)((total_threads + 255) / 256), 256, 0, stream>>>(
      (const uint4*)f16, edge_weight, edge_src, rp, out, n_nodes);
}